// Round 10
// baseline (409.353 us; speedup 1.0000x reference)
//
#include <hip/hip_runtime.h>
#include <math.h>

// KGVAE: 2-layer RelGraphConv (bdd) + reparameterize, R10.
// R10: explicit multi-deep weight-load pipeline in edge kernels (preload
// weight frags for 8/4 edges into regs, then consume), bf16 emb copy,
// bf16 h1 base (no fp32 h1 round-trip), fused cvt kernel.
// ws: h1bh[N*64]bf16 | h1h[N*64]bf16 | h2b[N*128]f32 | embh[N*64]bf16 |
//     w1h | w2h | pkA | pkB | norm_s | deg | fil | off | bsum

typedef __attribute__((ext_vector_type(8))) short bf16x8;
typedef __attribute__((ext_vector_type(4))) float f32x4;

__device__ __forceinline__ int bcasti(int v, int l) {
    return __builtin_amdgcn_readlane(v, l);
}
__device__ __forceinline__ float bcastf(float v, int l) {
    return __int_as_float(__builtin_amdgcn_readlane(__float_as_int(v), l));
}
__device__ __forceinline__ unsigned short f2bf(float f) {  // RTN bf16
    unsigned u = __float_as_uint(f);
    return (unsigned short)((u + 0x7FFFu + ((u >> 16) & 1u)) >> 16);
}
__device__ __forceinline__ float bfl(unsigned d) { return __uint_as_float(d << 16); }
__device__ __forceinline__ float bfh(unsigned d) { return __uint_as_float(d & 0xFFFF0000u); }
__device__ __forceinline__ float bfs(unsigned short s) { return __uint_as_float((unsigned)s << 16); }

__global__ void hist(const int* __restrict__ dst, int* __restrict__ deg, int e) {
    int i = blockIdx.x * blockDim.x + threadIdx.x;
    if (i < e) atomicAdd(&deg[dst[i]], 1);
}

__global__ void scan_part(const int* __restrict__ deg, int* __restrict__ bsum, int n) {
    __shared__ int sm[256];
    int t = threadIdx.x, g = blockIdx.x * 256 + t;
    sm[t] = (g < n) ? deg[g] : 0;
    __syncthreads();
    for (int d = 128; d > 0; d >>= 1) {
        if (t < d) sm[t] += sm[t + d];
        __syncthreads();
    }
    if (t == 0) bsum[blockIdx.x] = sm[0];
}

__global__ void scan_bsum(int* __restrict__ bsum, int* __restrict__ off, int nb, int n) {
    __shared__ int sm[256];
    int t = threadIdx.x;
    int v = (t < nb) ? bsum[t] : 0;
    sm[t] = v;
    __syncthreads();
    for (int d = 1; d < 256; d <<= 1) {
        int u = (t >= d) ? sm[t - d] : 0;
        __syncthreads();
        sm[t] += u;
        __syncthreads();
    }
    if (t < nb) bsum[t] = sm[t] - v;
    if (t == 255) off[n] = sm[255];
}

__global__ void scan_write(const int* __restrict__ deg, const int* __restrict__ bsum,
                           int* __restrict__ off, int n) {
    __shared__ int sm[256];
    int t = threadIdx.x, g = blockIdx.x * 256 + t;
    int v = (g < n) ? deg[g] : 0;
    sm[t] = v;
    __syncthreads();
    for (int d = 1; d < 256; d <<= 1) {
        int u = (t >= d) ? sm[t - d] : 0;
        __syncthreads();
        sm[t] += u;
        __syncthreads();
    }
    if (g < n) off[g] = bsum[blockIdx.x] + sm[t] - v;
}

__global__ void scatter_pack(const int* __restrict__ src, const int* __restrict__ dst,
                             const int* __restrict__ rel, const float* __restrict__ norm,
                             const int* __restrict__ h_ids, const int* __restrict__ off,
                             int* __restrict__ fil, unsigned* __restrict__ packA,
                             unsigned* __restrict__ packB, float* __restrict__ norm_s, int e) {
    int i = blockIdx.x * blockDim.x + threadIdx.x;
    if (i >= e) return;
    int d = dst[i];
    int p = off[d] + atomicAdd(&fil[d], 1);
    unsigned rhi = (unsigned)rel[i] << 16;
    int s = src[i];
    packA[p] = (unsigned)h_ids[s] | rhi;
    packB[p] = (unsigned)s | rhi;
    norm_s[p] = norm[i];
}

// fused bf16 conversion: w1, w2, emb
__global__ void cvt_all(const float* __restrict__ w1, const float* __restrict__ w2,
                        const float* __restrict__ emb, unsigned short* __restrict__ w1h,
                        unsigned short* __restrict__ w2h, unsigned short* __restrict__ embh,
                        int n1, int n2, int ne) {
    int i = blockIdx.x * blockDim.x + threadIdx.x;
    if (i < n1) w1h[i] = f2bf(w1[i]);
    else if (i < n1 + n2) w2h[i - n1] = f2bf(w2[i - n1]);
    else if (i < n1 + n2 + ne) embh[i - n1 - n2] = f2bf(emb[i - n1 - n2]);
}

// gemm1: h1bh[16-row tile] = bf16(b1 + embh[h_ids[row]] @ bf16(lw1))   (MFMA)
__global__ __launch_bounds__(256) void
gemm1_mfma(const unsigned short* __restrict__ embh, const int* __restrict__ h_ids,
           const float* __restrict__ lw1, const float* __restrict__ b1,
           unsigned short* __restrict__ h1bh, int n_nodes) {
    int w = threadIdx.x >> 6, l = threadIdx.x & 63;
    int lr = l & 15, lq = l >> 4;
    int rt = blockIdx.x;
    bf16x8 bfr[2];
    int coln = w * 16 + lr;
#pragma unroll
    for (int kb = 0; kb < 2; ++kb)
#pragma unroll
        for (int jj = 0; jj < 8; ++jj)
            bfr[kb][jj] = (short)f2bf(lw1[(kb * 32 + lq * 8 + jj) * 64 + coln]);
    int nrow = rt * 16 + lr;
    if (nrow >= n_nodes) nrow = n_nodes - 1;
    const unsigned short* arow = embh + (long)h_ids[nrow] * 64 + lq * 8;
    bf16x8 af0 = *(const bf16x8*)arow;
    bf16x8 af1 = *(const bf16x8*)(arow + 32);
    f32x4 acc = {0.f, 0.f, 0.f, 0.f};
    acc = __builtin_amdgcn_mfma_f32_16x16x32_bf16(af0, bfr[0], acc, 0, 0, 0);
    acc = __builtin_amdgcn_mfma_f32_16x16x32_bf16(af1, bfr[1], acc, 0, 0, 0);
    float bb = b1[coln];
#pragma unroll
    for (int r = 0; r < 4; ++r) {
        int row = rt * 16 + lq * 4 + r;
        if (row < n_nodes) h1bh[(long)row * 64 + coln] = f2bf(acc[r] + bb);
    }
}

// gemm2: h2b[16-row tile] = b2 + h1h @ bf16(lw2)  (MFMA)
__global__ __launch_bounds__(256) void
gemm2_mfma(const unsigned short* __restrict__ h1h, const float* __restrict__ lw2,
           const float* __restrict__ b2, float* __restrict__ h2b, int n_nodes) {
    int w = threadIdx.x >> 6, l = threadIdx.x & 63;
    int lr = l & 15, lq = l >> 4;
    int rt = blockIdx.x;
    bf16x8 bfr[2][2];
    int col0 = (2 * w) * 16 + lr, col1 = (2 * w + 1) * 16 + lr;
#pragma unroll
    for (int kb = 0; kb < 2; ++kb)
#pragma unroll
        for (int jj = 0; jj < 8; ++jj) {
            int k = kb * 32 + lq * 8 + jj;
            bfr[0][kb][jj] = (short)f2bf(lw2[k * 128 + col0]);
            bfr[1][kb][jj] = (short)f2bf(lw2[k * 128 + col1]);
        }
    int nrow = rt * 16 + lr;
    if (nrow >= n_nodes) nrow = n_nodes - 1;
    bf16x8 af0 = *(const bf16x8*)(h1h + (long)nrow * 64 + lq * 8);
    bf16x8 af1 = *(const bf16x8*)(h1h + (long)nrow * 64 + 32 + lq * 8);
    f32x4 acc0 = {0.f, 0.f, 0.f, 0.f}, acc1 = {0.f, 0.f, 0.f, 0.f};
    acc0 = __builtin_amdgcn_mfma_f32_16x16x32_bf16(af0, bfr[0][0], acc0, 0, 0, 0);
    acc0 = __builtin_amdgcn_mfma_f32_16x16x32_bf16(af1, bfr[0][1], acc0, 0, 0, 0);
    acc1 = __builtin_amdgcn_mfma_f32_16x16x32_bf16(af0, bfr[1][0], acc1, 0, 0, 0);
    acc1 = __builtin_amdgcn_mfma_f32_16x16x32_bf16(af1, bfr[1][1], acc1, 0, 0, 0);
    float bb0 = b2[col0], bb1 = b2[col1];
#pragma unroll
    for (int r = 0; r < 4; ++r) {
        int row = rt * 16 + lq * 4 + r;
        if (row < n_nodes) {
            h2b[(long)row * 128 + col0] = acc0[r] + bb0;
            h2b[(long)row * 128 + col1] = acc1[r] + bb1;
        }
    }
}

// butterfly transpose-reduce over 8-lane group
__device__ __forceinline__ float reduce8(float a0, float a1, float a2, float a3,
                                         float a4, float a5, float a6, float a7, int i) {
    int p1 = i & 1, p2 = (i >> 1) & 1, p3 = (i >> 2) & 1;
    float ka, sb, u0, u1, u2, u3, w0, w1;
    ka = p1 ? a1 : a0; sb = p1 ? a0 : a1; u0 = ka + __shfl_xor(sb, 1, 64);
    ka = p1 ? a3 : a2; sb = p1 ? a2 : a3; u1 = ka + __shfl_xor(sb, 1, 64);
    ka = p1 ? a5 : a4; sb = p1 ? a4 : a5; u2 = ka + __shfl_xor(sb, 1, 64);
    ka = p1 ? a7 : a6; sb = p1 ? a6 : a7; u3 = ka + __shfl_xor(sb, 1, 64);
    ka = p2 ? u1 : u0; sb = p2 ? u0 : u1; w0 = ka + __shfl_xor(sb, 2, 64);
    ka = p2 ? u3 : u2; sb = p2 ? u2 : u3; w1 = ka + __shfl_xor(sb, 2, 64);
    ka = p3 ? w1 : w0; sb = p3 ? w0 : w1;
    return ka + __shfl_xor(sb, 4, 64);
}

// edge1: h1h[n] = bf16(relu(h1bh[n] + sum_e nm * bdd(embh[pkA], w1h[rel])))
// weight pipeline: preload 8 edges' frags (uint4 each), then consume.
__global__ __launch_bounds__(256) void
edge1(const unsigned short* __restrict__ embh, const unsigned short* __restrict__ w1h,
      const unsigned short* __restrict__ h1bh, const int* __restrict__ off,
      const unsigned* __restrict__ packA, const float* __restrict__ norm_s,
      unsigned short* __restrict__ h1h, int n_nodes) {
    int tid = threadIdx.x;
    int w = tid >> 6, j = tid & 63, i = j & 7;
    int stride = gridDim.x * 4;
    const long woff = (long)j * 8;
    for (int n = blockIdx.x * 4 + w; n < n_nodes; n += stride) {
        float base = bfs(h1bh[(long)n * 64 + j]);  // issue early
        float a0 = 0.f, a1 = 0.f, a2 = 0.f, a3 = 0.f, a4 = 0.f, a5 = 0.f, a6 = 0.f, a7 = 0.f;
        int e0 = off[n], e1v = off[n + 1];
        for (int win = e0; win < e1v; win += 64) {
            int wcnt = e1v - win; if (wcnt > 64) wcnt = 64;
            unsigned u = (j < wcnt) ? packA[win + j] : 0u;
            float nmv = (j < wcnt) ? norm_s[win + j] : 0.f;
            for (int b16 = 0; b16 < wcnt; b16 += 16) {
                int cnt = wcnt - b16; if (cnt > 16) cnt = 16;
                float xs[16];
                int rr[16];
#pragma unroll
                for (int c = 0; c < 16; ++c)
                    if (c < cnt) {
                        int uc = bcasti((int)u, b16 + c);
                        xs[c] = bfs(embh[(long)(uc & 0xFFFF) * 64 + j]);
                        rr[c] = uc >> 16;
                    }
                for (int g = 0; g < 16; g += 8) {
                    if (g >= cnt) break;
                    uint4 wd[8];
#pragma unroll
                    for (int q = 0; q < 8; ++q)
                        if (g + q < cnt)
                            wd[q] = *(const uint4*)(w1h + (long)rr[g + q] * 512 + woff);
#pragma unroll
                    for (int q = 0; q < 8; ++q)
                        if (g + q < cnt) {
                            float nm = bcastf(nmv, b16 + g + q);
                            float xm = xs[g + q] * nm;
                            uint4 wv = wd[q];
                            a0 = fmaf(xm, bfl(wv.x), a0); a1 = fmaf(xm, bfh(wv.x), a1);
                            a2 = fmaf(xm, bfl(wv.y), a2); a3 = fmaf(xm, bfh(wv.y), a3);
                            a4 = fmaf(xm, bfl(wv.z), a4); a5 = fmaf(xm, bfh(wv.z), a5);
                            a6 = fmaf(xm, bfl(wv.w), a6); a7 = fmaf(xm, bfh(wv.w), a7);
                        }
                }
            }
        }
        float agg = reduce8(a0, a1, a2, a3, a4, a5, a6, a7, i);
        h1h[(long)n * 64 + j] = f2bf(fmaxf(base + agg, 0.f));
    }
}

// edge2: out = reparam(h2b[n] + sum_e nm * bdd(h1h[src], w2h[rel]))
// weight pipeline: preload 4 edges' frags (2x uint4 each), then consume.
__global__ __launch_bounds__(256) void
edge2(const unsigned short* __restrict__ h1h, const unsigned short* __restrict__ w2h,
      const float* __restrict__ h2b, const float* __restrict__ eps,
      const int* __restrict__ off, const unsigned* __restrict__ packB,
      const float* __restrict__ norm_s, float* __restrict__ out, int n_nodes) {
    int tid = threadIdx.x;
    int w = tid >> 6, j = tid & 63;
    int i = j & 7, b = j >> 3;
    int o1 = b * 16 + i, o2 = o1 + 8;
    int stride = gridDim.x * 4;
    const long woff = (long)j * 16;
    for (int n = blockIdx.x * 4 + w; n < n_nodes; n += stride) {
        float base1 = h2b[(long)n * 128 + o1];
        float base2 = h2b[(long)n * 128 + o2];
        float a[16];
#pragma unroll
        for (int q = 0; q < 16; ++q) a[q] = 0.f;
        int e0 = off[n], e1v = off[n + 1];
        for (int win = e0; win < e1v; win += 64) {
            int wcnt = e1v - win; if (wcnt > 64) wcnt = 64;
            unsigned u = (j < wcnt) ? packB[win + j] : 0u;
            float nmv = (j < wcnt) ? norm_s[win + j] : 0.f;
            for (int b16 = 0; b16 < wcnt; b16 += 16) {
                int cnt = wcnt - b16; if (cnt > 16) cnt = 16;
                float xs[16];
                int rr[16];
#pragma unroll
                for (int c = 0; c < 16; ++c)
                    if (c < cnt) {
                        int uc = bcasti((int)u, b16 + c);
                        xs[c] = bfs(h1h[(long)(uc & 0xFFFF) * 64 + j]);
                        rr[c] = uc >> 16;
                    }
                for (int g = 0; g < 16; g += 4) {
                    if (g >= cnt) break;
                    uint4 wa[4], wb[4];
#pragma unroll
                    for (int q = 0; q < 4; ++q)
                        if (g + q < cnt) {
                            const uint4* p = (const uint4*)(w2h + (long)rr[g + q] * 1024 + woff);
                            wa[q] = p[0];
                            wb[q] = p[1];
                        }
#pragma unroll
                    for (int q = 0; q < 4; ++q)
                        if (g + q < cnt) {
                            float nm = bcastf(nmv, b16 + g + q);
                            float xm = xs[g + q] * nm;
                            uint4 va = wa[q], vb = wb[q];
                            a[0] = fmaf(xm, bfl(va.x), a[0]);   a[1] = fmaf(xm, bfh(va.x), a[1]);
                            a[2] = fmaf(xm, bfl(va.y), a[2]);   a[3] = fmaf(xm, bfh(va.y), a[3]);
                            a[4] = fmaf(xm, bfl(va.z), a[4]);   a[5] = fmaf(xm, bfh(va.z), a[5]);
                            a[6] = fmaf(xm, bfl(va.w), a[6]);   a[7] = fmaf(xm, bfh(va.w), a[7]);
                            a[8] = fmaf(xm, bfl(vb.x), a[8]);   a[9] = fmaf(xm, bfh(vb.x), a[9]);
                            a[10] = fmaf(xm, bfl(vb.y), a[10]); a[11] = fmaf(xm, bfh(vb.y), a[11]);
                            a[12] = fmaf(xm, bfl(vb.z), a[12]); a[13] = fmaf(xm, bfh(vb.z), a[13]);
                            a[14] = fmaf(xm, bfl(vb.w), a[14]); a[15] = fmaf(xm, bfh(vb.w), a[15]);
                        }
                }
            }
        }
        float r1 = reduce8(a[0], a[1], a[2], a[3], a[4], a[5], a[6], a[7], i);
        float r2 = reduce8(a[8], a[9], a[10], a[11], a[12], a[13], a[14], a[15], i);
        float v1 = r1 + base1;
        float v2 = r2 + base2;
        float p1 = __shfl_xor(v1, 32, 64);
        float p2 = __shfl_xor(v2, 32, 64);
        if (j < 32) {
            long basep = (long)n * 64;
            float sp1 = (p1 > 20.f) ? p1 : log1pf(expf(p1));
            float sp2 = (p2 > 20.f) ? p2 : log1pf(expf(p2));
            out[basep + o1] = fmaf(sqrtf(sp1 + 1e-8f), eps[basep + o1], v1);
            out[basep + o2] = fmaf(sqrtf(sp2 + 1e-8f), eps[basep + o2], v2);
        }
    }
}

extern "C" void kernel_launch(void* const* d_in, const int* in_sizes, int n_in,
                              void* d_out, int out_size, void* d_ws, size_t ws_size,
                              hipStream_t stream) {
    const float* emb   = (const float*)d_in[0];
    const float* norm  = (const float*)d_in[1];
    const float* eps   = (const float*)d_in[2];
    const float* w1    = (const float*)d_in[3];
    const float* lw1   = (const float*)d_in[4];
    const float* b1    = (const float*)d_in[5];
    const float* w2    = (const float*)d_in[6];
    const float* lw2   = (const float*)d_in[7];
    const float* b2    = (const float*)d_in[8];
    const int*   h_ids = (const int*)d_in[9];
    const int*   src   = (const int*)d_in[10];
    const int*   dst   = (const int*)d_in[11];
    const int*   rel   = (const int*)d_in[12];
    float* out = (float*)d_out;

    int n_nodes = in_sizes[0] / 64;   // 50000
    int n_edges = in_sizes[10];       // 400000
    int nw1 = in_sizes[3];            // 200*512
    int nw2 = in_sizes[6];            // 200*1024
    int ne  = in_sizes[0];            // N*64

    char* ws = (char*)d_ws;
    unsigned short* h1bh = (unsigned short*)ws;       ws += (size_t)n_nodes * 64 * 2;
    unsigned short* h1h  = (unsigned short*)ws;       ws += (size_t)n_nodes * 64 * 2;
    float* h2b    = (float*)ws;                       ws += (size_t)n_nodes * 128 * 4;
    unsigned short* embh = (unsigned short*)ws;       ws += (size_t)ne * 2;
    unsigned short* w1h  = (unsigned short*)ws;       ws += (size_t)nw1 * 2;
    unsigned short* w2h  = (unsigned short*)ws;       ws += (size_t)nw2 * 2;
    unsigned* pkA = (unsigned*)ws;                    ws += (size_t)n_edges * 4;
    unsigned* pkB = (unsigned*)ws;                    ws += (size_t)n_edges * 4;
    float* norm_s = (float*)ws;                       ws += (size_t)n_edges * 4;
    int*   deg    = (int*)ws;                         ws += (size_t)n_nodes * 4;
    int*   fil    = (int*)ws;                         ws += (size_t)n_nodes * 4;
    int*   off    = (int*)ws;                         ws += (size_t)(n_nodes + 1) * 4;
    int*   bsum   = (int*)ws;

    int blk = 256;
    int nb = (n_nodes + 255) / 256;
    int nt = (n_nodes + 15) / 16;
    // CSR build + bf16 conversions
    hipMemsetAsync(deg, 0, (size_t)n_nodes * 8, stream);
    cvt_all<<<(nw1 + nw2 + ne + blk - 1) / blk, blk, 0, stream>>>(w1, w2, emb, w1h, w2h, embh, nw1, nw2, ne);
    hist<<<(n_edges + blk - 1) / blk, blk, 0, stream>>>(dst, deg, n_edges);
    scan_part<<<nb, 256, 0, stream>>>(deg, bsum, n_nodes);
    scan_bsum<<<1, 256, 0, stream>>>(bsum, off, nb, n_nodes);
    scan_write<<<nb, 256, 0, stream>>>(deg, bsum, off, n_nodes);
    scatter_pack<<<(n_edges + blk - 1) / blk, blk, 0, stream>>>(src, dst, rel, norm, h_ids, off, fil, pkA, pkB, norm_s, n_edges);
    // layer 1
    gemm1_mfma<<<nt, blk, 0, stream>>>(embh, h_ids, lw1, b1, h1bh, n_nodes);
    edge1<<<4096, blk, 0, stream>>>(embh, w1h, h1bh, off, pkA, norm_s, h1h, n_nodes);
    // layer 2
    gemm2_mfma<<<nt, blk, 0, stream>>>(h1h, lw2, b2, h2b, n_nodes);
    edge2<<<4096, blk, 0, stream>>>(h1h, w2h, h2b, eps, off, pkB, norm_s, out, n_nodes);
}

// Round 11
// 345.537 us; speedup vs baseline: 1.1847x; 1.1847x over previous
//
#include <hip/hip_runtime.h>
#include <math.h>

// KGVAE: 2-layer RelGraphConv (bdd) + reparameterize, R11.
// R9 edge structure (inline weight consume, 16-deep gathers) + bf16 embh/h1bh/
// h2bh + packed v_pk_fma_f32 inner loop (float2 accumulators) + grid 8192.
// ws: h1bh | h1h | h2bh | embh | w1h | w2h | pkA | pkB | norm_s | deg fil | off | bsum

typedef __attribute__((ext_vector_type(8))) short bf16x8;
typedef __attribute__((ext_vector_type(4))) float f32x4;
typedef __attribute__((ext_vector_type(2))) float v2f;

__device__ __forceinline__ int bcasti(int v, int l) {
    return __builtin_amdgcn_readlane(v, l);
}
__device__ __forceinline__ float bcastf(float v, int l) {
    return __int_as_float(__builtin_amdgcn_readlane(__float_as_int(v), l));
}
__device__ __forceinline__ unsigned short f2bf(float f) {  // RTN bf16
    unsigned u = __float_as_uint(f);
    return (unsigned short)((u + 0x7FFFu + ((u >> 16) & 1u)) >> 16);
}
__device__ __forceinline__ float bfs(unsigned short s) { return __uint_as_float((unsigned)s << 16); }
__device__ __forceinline__ v2f bf2(unsigned u) {  // 2 packed bf16 -> float2
    v2f r;
    r.x = __uint_as_float(u << 16);
    r.y = __uint_as_float(u & 0xFFFF0000u);
    return r;
}

__global__ void hist(const int* __restrict__ dst, int* __restrict__ deg, int e) {
    int i = blockIdx.x * blockDim.x + threadIdx.x;
    if (i < e) atomicAdd(&deg[dst[i]], 1);
}

__global__ void scan_part(const int* __restrict__ deg, int* __restrict__ bsum, int n) {
    __shared__ int sm[256];
    int t = threadIdx.x, g = blockIdx.x * 256 + t;
    sm[t] = (g < n) ? deg[g] : 0;
    __syncthreads();
    for (int d = 128; d > 0; d >>= 1) {
        if (t < d) sm[t] += sm[t + d];
        __syncthreads();
    }
    if (t == 0) bsum[blockIdx.x] = sm[0];
}

__global__ void scan_bsum(int* __restrict__ bsum, int* __restrict__ off, int nb, int n) {
    __shared__ int sm[256];
    int t = threadIdx.x;
    int v = (t < nb) ? bsum[t] : 0;
    sm[t] = v;
    __syncthreads();
    for (int d = 1; d < 256; d <<= 1) {
        int u = (t >= d) ? sm[t - d] : 0;
        __syncthreads();
        sm[t] += u;
        __syncthreads();
    }
    if (t < nb) bsum[t] = sm[t] - v;
    if (t == 255) off[n] = sm[255];
}

__global__ void scan_write(const int* __restrict__ deg, const int* __restrict__ bsum,
                           int* __restrict__ off, int n) {
    __shared__ int sm[256];
    int t = threadIdx.x, g = blockIdx.x * 256 + t;
    int v = (g < n) ? deg[g] : 0;
    sm[t] = v;
    __syncthreads();
    for (int d = 1; d < 256; d <<= 1) {
        int u = (t >= d) ? sm[t - d] : 0;
        __syncthreads();
        sm[t] += u;
        __syncthreads();
    }
    if (g < n) off[g] = bsum[blockIdx.x] + sm[t] - v;
}

__global__ void scatter_pack(const int* __restrict__ src, const int* __restrict__ dst,
                             const int* __restrict__ rel, const float* __restrict__ norm,
                             const int* __restrict__ h_ids, const int* __restrict__ off,
                             int* __restrict__ fil, unsigned* __restrict__ packA,
                             unsigned* __restrict__ packB, float* __restrict__ norm_s, int e) {
    int i = blockIdx.x * blockDim.x + threadIdx.x;
    if (i >= e) return;
    int d = dst[i];
    int p = off[d] + atomicAdd(&fil[d], 1);
    unsigned rhi = (unsigned)rel[i] << 16;
    int s = src[i];
    packA[p] = (unsigned)h_ids[s] | rhi;
    packB[p] = (unsigned)s | rhi;
    norm_s[p] = norm[i];
}

// fused bf16 conversion: w1, w2, emb
__global__ void cvt_all(const float* __restrict__ w1, const float* __restrict__ w2,
                        const float* __restrict__ emb, unsigned short* __restrict__ w1h,
                        unsigned short* __restrict__ w2h, unsigned short* __restrict__ embh,
                        int n1, int n2, int ne) {
    int i = blockIdx.x * blockDim.x + threadIdx.x;
    if (i < n1) w1h[i] = f2bf(w1[i]);
    else if (i < n1 + n2) w2h[i - n1] = f2bf(w2[i - n1]);
    else if (i < n1 + n2 + ne) embh[i - n1 - n2] = f2bf(emb[i - n1 - n2]);
}

// gemm1: h1bh[16-row tile] = bf16(b1 + embh[h_ids[row]] @ bf16(lw1))   (MFMA)
__global__ __launch_bounds__(256) void
gemm1_mfma(const unsigned short* __restrict__ embh, const int* __restrict__ h_ids,
           const float* __restrict__ lw1, const float* __restrict__ b1,
           unsigned short* __restrict__ h1bh, int n_nodes) {
    int w = threadIdx.x >> 6, l = threadIdx.x & 63;
    int lr = l & 15, lq = l >> 4;
    int rt = blockIdx.x;
    bf16x8 bfr[2];
    int coln = w * 16 + lr;
#pragma unroll
    for (int kb = 0; kb < 2; ++kb)
#pragma unroll
        for (int jj = 0; jj < 8; ++jj)
            bfr[kb][jj] = (short)f2bf(lw1[(kb * 32 + lq * 8 + jj) * 64 + coln]);
    int nrow = rt * 16 + lr;
    if (nrow >= n_nodes) nrow = n_nodes - 1;
    const unsigned short* arow = embh + (long)h_ids[nrow] * 64 + lq * 8;
    bf16x8 af0 = *(const bf16x8*)arow;
    bf16x8 af1 = *(const bf16x8*)(arow + 32);
    f32x4 acc = {0.f, 0.f, 0.f, 0.f};
    acc = __builtin_amdgcn_mfma_f32_16x16x32_bf16(af0, bfr[0], acc, 0, 0, 0);
    acc = __builtin_amdgcn_mfma_f32_16x16x32_bf16(af1, bfr[1], acc, 0, 0, 0);
    float bb = b1[coln];
#pragma unroll
    for (int r = 0; r < 4; ++r) {
        int row = rt * 16 + lq * 4 + r;
        if (row < n_nodes) h1bh[(long)row * 64 + coln] = f2bf(acc[r] + bb);
    }
}

// gemm2: h2bh[16-row tile] = bf16(b2 + h1h @ bf16(lw2))  (MFMA)
__global__ __launch_bounds__(256) void
gemm2_mfma(const unsigned short* __restrict__ h1h, const float* __restrict__ lw2,
           const float* __restrict__ b2, unsigned short* __restrict__ h2bh, int n_nodes) {
    int w = threadIdx.x >> 6, l = threadIdx.x & 63;
    int lr = l & 15, lq = l >> 4;
    int rt = blockIdx.x;
    bf16x8 bfr[2][2];
    int col0 = (2 * w) * 16 + lr, col1 = (2 * w + 1) * 16 + lr;
#pragma unroll
    for (int kb = 0; kb < 2; ++kb)
#pragma unroll
        for (int jj = 0; jj < 8; ++jj) {
            int k = kb * 32 + lq * 8 + jj;
            bfr[0][kb][jj] = (short)f2bf(lw2[k * 128 + col0]);
            bfr[1][kb][jj] = (short)f2bf(lw2[k * 128 + col1]);
        }
    int nrow = rt * 16 + lr;
    if (nrow >= n_nodes) nrow = n_nodes - 1;
    bf16x8 af0 = *(const bf16x8*)(h1h + (long)nrow * 64 + lq * 8);
    bf16x8 af1 = *(const bf16x8*)(h1h + (long)nrow * 64 + 32 + lq * 8);
    f32x4 acc0 = {0.f, 0.f, 0.f, 0.f}, acc1 = {0.f, 0.f, 0.f, 0.f};
    acc0 = __builtin_amdgcn_mfma_f32_16x16x32_bf16(af0, bfr[0][0], acc0, 0, 0, 0);
    acc0 = __builtin_amdgcn_mfma_f32_16x16x32_bf16(af1, bfr[0][1], acc0, 0, 0, 0);
    acc1 = __builtin_amdgcn_mfma_f32_16x16x32_bf16(af0, bfr[1][0], acc1, 0, 0, 0);
    acc1 = __builtin_amdgcn_mfma_f32_16x16x32_bf16(af1, bfr[1][1], acc1, 0, 0, 0);
    float bb0 = b2[col0], bb1 = b2[col1];
#pragma unroll
    for (int r = 0; r < 4; ++r) {
        int row = rt * 16 + lq * 4 + r;
        if (row < n_nodes) {
            h2bh[(long)row * 128 + col0] = f2bf(acc0[r] + bb0);
            h2bh[(long)row * 128 + col1] = f2bf(acc1[r] + bb1);
        }
    }
}

// butterfly transpose-reduce over 8-lane group
__device__ __forceinline__ float reduce8(float a0, float a1, float a2, float a3,
                                         float a4, float a5, float a6, float a7, int i) {
    int p1 = i & 1, p2 = (i >> 1) & 1, p3 = (i >> 2) & 1;
    float ka, sb, u0, u1, u2, u3, w0, w1;
    ka = p1 ? a1 : a0; sb = p1 ? a0 : a1; u0 = ka + __shfl_xor(sb, 1, 64);
    ka = p1 ? a3 : a2; sb = p1 ? a2 : a3; u1 = ka + __shfl_xor(sb, 1, 64);
    ka = p1 ? a5 : a4; sb = p1 ? a4 : a5; u2 = ka + __shfl_xor(sb, 1, 64);
    ka = p1 ? a7 : a6; sb = p1 ? a6 : a7; u3 = ka + __shfl_xor(sb, 1, 64);
    ka = p2 ? u1 : u0; sb = p2 ? u0 : u1; w0 = ka + __shfl_xor(sb, 2, 64);
    ka = p2 ? u3 : u2; sb = p2 ? u2 : u3; w1 = ka + __shfl_xor(sb, 2, 64);
    ka = p3 ? w1 : w0; sb = p3 ? w0 : w1;
    return ka + __shfl_xor(sb, 4, 64);
}

// edge1: h1h[n] = bf16(relu(h1bh[n] + sum_e nm * bdd(embh[pkA], w1h[rel])))
__global__ __launch_bounds__(256) void
edge1(const unsigned short* __restrict__ embh, const unsigned short* __restrict__ w1h,
      const unsigned short* __restrict__ h1bh, const int* __restrict__ off,
      const unsigned* __restrict__ packA, const float* __restrict__ norm_s,
      unsigned short* __restrict__ h1h, int n_nodes) {
    int tid = threadIdx.x;
    int w = tid >> 6, j = tid & 63, i = j & 7;
    int stride = gridDim.x * 4;
    const long woff = (long)j * 8;
    for (int n = blockIdx.x * 4 + w; n < n_nodes; n += stride) {
        float base = bfs(h1bh[(long)n * 64 + j]);  // issue early
        v2f acc[4];
#pragma unroll
        for (int q = 0; q < 4; ++q) acc[q] = (v2f){0.f, 0.f};
        int e0 = off[n], e1v = off[n + 1];
        for (int win = e0; win < e1v; win += 64) {
            int wcnt = e1v - win; if (wcnt > 64) wcnt = 64;
            unsigned u = (j < wcnt) ? packA[win + j] : 0u;
            float nmv = (j < wcnt) ? norm_s[win + j] : 0.f;
            for (int b16 = 0; b16 < wcnt; b16 += 16) {
                int cnt = wcnt - b16; if (cnt > 16) cnt = 16;
                float xs[16];
                int rr[16];
#pragma unroll
                for (int c = 0; c < 16; ++c)
                    if (c < cnt) {
                        int uc = bcasti((int)u, b16 + c);
                        xs[c] = bfs(embh[(long)(uc & 0xFFFF) * 64 + j]);
                        rr[c] = uc >> 16;
                    }
#pragma unroll
                for (int c = 0; c < 16; ++c)
                    if (c < cnt) {
                        float nm = bcastf(nmv, b16 + c);
                        uint4 wd = *(const uint4*)(w1h + (long)rr[c] * 512 + woff);
                        float xm = xs[c] * nm;
                        v2f xm2 = {xm, xm};
                        acc[0] += xm2 * bf2(wd.x);
                        acc[1] += xm2 * bf2(wd.y);
                        acc[2] += xm2 * bf2(wd.z);
                        acc[3] += xm2 * bf2(wd.w);
                    }
            }
        }
        float agg = reduce8(acc[0].x, acc[0].y, acc[1].x, acc[1].y,
                            acc[2].x, acc[2].y, acc[3].x, acc[3].y, i);
        h1h[(long)n * 64 + j] = f2bf(fmaxf(base + agg, 0.f));
    }
}

// edge2: out = reparam(h2bh[n] + sum_e nm * bdd(h1h[src], w2h[rel]))
__global__ __launch_bounds__(256) void
edge2(const unsigned short* __restrict__ h1h, const unsigned short* __restrict__ w2h,
      const unsigned short* __restrict__ h2bh, const float* __restrict__ eps,
      const int* __restrict__ off, const unsigned* __restrict__ packB,
      const float* __restrict__ norm_s, float* __restrict__ out, int n_nodes) {
    int tid = threadIdx.x;
    int w = tid >> 6, j = tid & 63;
    int i = j & 7, b = j >> 3;
    int o1 = b * 16 + i, o2 = o1 + 8;
    int stride = gridDim.x * 4;
    const long woff = (long)j * 16;
    for (int n = blockIdx.x * 4 + w; n < n_nodes; n += stride) {
        float base1 = bfs(h2bh[(long)n * 128 + o1]);  // issue early
        float base2 = bfs(h2bh[(long)n * 128 + o2]);
        v2f acc[8];
#pragma unroll
        for (int q = 0; q < 8; ++q) acc[q] = (v2f){0.f, 0.f};
        int e0 = off[n], e1v = off[n + 1];
        for (int win = e0; win < e1v; win += 64) {
            int wcnt = e1v - win; if (wcnt > 64) wcnt = 64;
            unsigned u = (j < wcnt) ? packB[win + j] : 0u;
            float nmv = (j < wcnt) ? norm_s[win + j] : 0.f;
            for (int b16 = 0; b16 < wcnt; b16 += 16) {
                int cnt = wcnt - b16; if (cnt > 16) cnt = 16;
                float xs[16];
                int rr[16];
#pragma unroll
                for (int c = 0; c < 16; ++c)
                    if (c < cnt) {
                        int uc = bcasti((int)u, b16 + c);
                        xs[c] = bfs(h1h[(long)(uc & 0xFFFF) * 64 + j]);
                        rr[c] = uc >> 16;
                    }
#pragma unroll
                for (int c = 0; c < 16; ++c)
                    if (c < cnt) {
                        float nm = bcastf(nmv, b16 + c);
                        const uint4* p = (const uint4*)(w2h + (long)rr[c] * 1024 + woff);
                        uint4 wa = p[0], wb = p[1];
                        float xm = xs[c] * nm;
                        v2f xm2 = {xm, xm};
                        acc[0] += xm2 * bf2(wa.x);
                        acc[1] += xm2 * bf2(wa.y);
                        acc[2] += xm2 * bf2(wa.z);
                        acc[3] += xm2 * bf2(wa.w);
                        acc[4] += xm2 * bf2(wb.x);
                        acc[5] += xm2 * bf2(wb.y);
                        acc[6] += xm2 * bf2(wb.z);
                        acc[7] += xm2 * bf2(wb.w);
                    }
            }
        }
        float r1 = reduce8(acc[0].x, acc[0].y, acc[1].x, acc[1].y,
                           acc[2].x, acc[2].y, acc[3].x, acc[3].y, i);
        float r2 = reduce8(acc[4].x, acc[4].y, acc[5].x, acc[5].y,
                           acc[6].x, acc[6].y, acc[7].x, acc[7].y, i);
        float v1 = r1 + base1;
        float v2 = r2 + base2;
        float p1 = __shfl_xor(v1, 32, 64);
        float p2 = __shfl_xor(v2, 32, 64);
        if (j < 32) {
            long basep = (long)n * 64;
            float sp1 = (p1 > 20.f) ? p1 : log1pf(expf(p1));
            float sp2 = (p2 > 20.f) ? p2 : log1pf(expf(p2));
            out[basep + o1] = fmaf(sqrtf(sp1 + 1e-8f), eps[basep + o1], v1);
            out[basep + o2] = fmaf(sqrtf(sp2 + 1e-8f), eps[basep + o2], v2);
        }
    }
}

extern "C" void kernel_launch(void* const* d_in, const int* in_sizes, int n_in,
                              void* d_out, int out_size, void* d_ws, size_t ws_size,
                              hipStream_t stream) {
    const float* emb   = (const float*)d_in[0];
    const float* norm  = (const float*)d_in[1];
    const float* eps   = (const float*)d_in[2];
    const float* w1    = (const float*)d_in[3];
    const float* lw1   = (const float*)d_in[4];
    const float* b1    = (const float*)d_in[5];
    const float* w2    = (const float*)d_in[6];
    const float* lw2   = (const float*)d_in[7];
    const float* b2    = (const float*)d_in[8];
    const int*   h_ids = (const int*)d_in[9];
    const int*   src   = (const int*)d_in[10];
    const int*   dst   = (const int*)d_in[11];
    const int*   rel   = (const int*)d_in[12];
    float* out = (float*)d_out;

    int n_nodes = in_sizes[0] / 64;   // 50000
    int n_edges = in_sizes[10];       // 400000
    int nw1 = in_sizes[3];            // 200*512
    int nw2 = in_sizes[6];            // 200*1024
    int ne  = in_sizes[0];            // N*64

    char* ws = (char*)d_ws;
    unsigned short* h1bh = (unsigned short*)ws;       ws += (size_t)n_nodes * 64 * 2;
    unsigned short* h1h  = (unsigned short*)ws;       ws += (size_t)n_nodes * 64 * 2;
    unsigned short* h2bh = (unsigned short*)ws;       ws += (size_t)n_nodes * 128 * 2;
    unsigned short* embh = (unsigned short*)ws;       ws += (size_t)ne * 2;
    unsigned short* w1h  = (unsigned short*)ws;       ws += (size_t)nw1 * 2;
    unsigned short* w2h  = (unsigned short*)ws;       ws += (size_t)nw2 * 2;
    unsigned* pkA = (unsigned*)ws;                    ws += (size_t)n_edges * 4;
    unsigned* pkB = (unsigned*)ws;                    ws += (size_t)n_edges * 4;
    float* norm_s = (float*)ws;                       ws += (size_t)n_edges * 4;
    int*   deg    = (int*)ws;                         ws += (size_t)n_nodes * 4;
    int*   fil    = (int*)ws;                         ws += (size_t)n_nodes * 4;
    int*   off    = (int*)ws;                         ws += (size_t)(n_nodes + 1) * 4;
    int*   bsum   = (int*)ws;

    int blk = 256;
    int nb = (n_nodes + 255) / 256;
    int nt = (n_nodes + 15) / 16;
    // CSR build + bf16 conversions
    hipMemsetAsync(deg, 0, (size_t)n_nodes * 8, stream);
    cvt_all<<<(nw1 + nw2 + ne + blk - 1) / blk, blk, 0, stream>>>(w1, w2, emb, w1h, w2h, embh, nw1, nw2, ne);
    hist<<<(n_edges + blk - 1) / blk, blk, 0, stream>>>(dst, deg, n_edges);
    scan_part<<<nb, 256, 0, stream>>>(deg, bsum, n_nodes);
    scan_bsum<<<1, 256, 0, stream>>>(bsum, off, nb, n_nodes);
    scan_write<<<nb, 256, 0, stream>>>(deg, bsum, off, n_nodes);
    scatter_pack<<<(n_edges + blk - 1) / blk, blk, 0, stream>>>(src, dst, rel, norm, h_ids, off, fil, pkA, pkB, norm_s, n_edges);
    // layer 1
    gemm1_mfma<<<nt, blk, 0, stream>>>(embh, h_ids, lw1, b1, h1bh, n_nodes);
    edge1<<<8192, blk, 0, stream>>>(embh, w1h, h1bh, off, pkA, norm_s, h1h, n_nodes);
    // layer 2
    gemm2_mfma<<<nt, blk, 0, stream>>>(h1h, lw2, b2, h2bh, n_nodes);
    edge2<<<8192, blk, 0, stream>>>(h1h, w2h, h2bh, eps, off, pkB, norm_s, out, n_nodes);
}